// Round 1
// 105.201 us; speedup vs baseline: 1.1000x; 1.1000x over previous
//
#include <hip/hip_runtime.h>
#include <hip/hip_bf16.h>

#define CC 64
#define NN 4096   // H*W
#define MM 1024   // pooled pixels

typedef __attribute__((ext_vector_type(4))) short s4b;      // 4 bf16 = 2 VGPRs
typedef __attribute__((ext_vector_type(8))) short s8b;      // 8 bf16 = 4 VGPRs
typedef __attribute__((ext_vector_type(4))) float float4v;  // MFMA C/D frag

__device__ inline unsigned short f2bf(float f) {
    union { float f; unsigned u; } v; v.f = f;
    unsigned r = v.u + 0x7fff + ((v.u >> 16) & 1);   // RNE
    return (unsigned short)(r >> 16);
}

__device__ inline float4v mfma16(s4b a, s4b b, float4v c) {
#if __has_builtin(__builtin_amdgcn_mfma_f32_16x16x16bf16_1k)
    return __builtin_amdgcn_mfma_f32_16x16x16bf16_1k(a, b, c, 0, 0, 0);
#else
    float4v d;
    asm volatile("v_mfma_f32_16x16x16_bf16 %0, %1, %2, %3"
                 : "=v"(d) : "v"(a), "v"(b), "v"(c));
    return d;
#endif
}

__device__ inline float4v mfma32(s8b a, s8b b, float4v c) {
#if __has_builtin(__builtin_amdgcn_mfma_f32_16x16x32_bf16)
    return __builtin_amdgcn_mfma_f32_16x16x32_bf16(a, b, c, 0, 0, 0);
#else
    float4v d;
    asm volatile("v_mfma_f32_16x16x32_bf16 %0, %1, %2, %3"
                 : "=v"(d) : "v"(a), "v"(b), "v"(c));
    return d;
#endif
}

// ---------------------------------------------------------------------------
// prep_kernel v2 (unchanged): 2 c-halves per pixel (reduced via LDS).
// Block: 256 thr = 128 pixels (2 rows x 64 cols) x 2 c-halves. Grid (32,16).
// Outputs: thT [b][n][8] bf16 (x log2e); phiP [b][m][8]; gP [b][gi][m].
// ---------------------------------------------------------------------------
__global__ __launch_bounds__(256) void prep_kernel(
    const float* __restrict__ x,
    const float* __restrict__ Wth,
    const float* __restrict__ Wph,
    const float* __restrict__ Wg,
    unsigned short* __restrict__ thT,
    unsigned short* __restrict__ phiP,
    unsigned short* __restrict__ gP)
{
    __shared__ float wt[64 * 48];       // 12.3 KB
    __shared__ float buf[128 * 49];     // 25.1 KB (partials, then pool)

    const int tid  = threadIdx.x;
    const int b    = blockIdx.y;
    const int hp   = blockIdx.x;        // row-pair 0..31
    const int pix  = tid & 127;         // 2 rows x 64 cols
    const int half = tid >> 7;          // c-half (wave-uniform)

    for (int idx = tid; idx < 64 * 48; idx += 256) {
        const int c = idx / 48, j = idx % 48;
        float v;
        if (j < 8)       v = Wth[j * 64 + c];
        else if (j < 16) v = Wph[(j - 8) * 64 + c];
        else             v = Wg[(j - 16) * 64 + c];
        wt[c * 48 + j] = v;
    }
    __syncthreads();

    const int n = (2 * hp + (pix >> 6)) * 64 + (pix & 63);
    const float* xb = x + (size_t)b * CC * NN + (size_t)half * 32 * NN + n;

    float acc[48];
#pragma unroll
    for (int j = 0; j < 48; ++j) acc[j] = 0.f;

#pragma unroll
    for (int c0 = 0; c0 < 32; c0 += 16) {
        float xv[16];
#pragma unroll
        for (int u = 0; u < 16; ++u) xv[u] = xb[(size_t)(c0 + u) * NN];
#pragma unroll
        for (int u = 0; u < 16; ++u) {
            const float* wrow = &wt[(half * 32 + c0 + u) * 48];
#pragma unroll
            for (int j = 0; j < 48; ++j) acc[j] += wrow[j] * xv[u];
        }
    }

    if (half == 1) {
#pragma unroll
        for (int j = 0; j < 48; ++j) buf[pix * 49 + j] = acc[j];
    }
    __syncthreads();

    if (half == 0) {
#pragma unroll
        for (int j = 0; j < 48; ++j) acc[j] += buf[pix * 49 + j];
        // theta out (bf16, scaled by log2 e)
        union { unsigned short s[8]; uint4 v; } pk;
#pragma unroll
        for (int j = 0; j < 8; ++j) pk.s[j] = f2bf(acc[j] * 1.44269504f);
        *(uint4*)&thT[((size_t)b * NN + n) * 8] = pk.v;
        // stash phi/g pre-pool values (overwrite own partial region)
#pragma unroll
        for (int j = 0; j < 40; ++j) buf[pix * 49 + j] = acc[8 + j];
    }
    __syncthreads();

    // 2x2 pool: 32 pooled cols x 40 channels
    for (int idx = tid; idx < 1280; idx += 256) {
        const int pm = idx & 31;        // pooled col
        const int j  = idx >> 5;        // channel 0..39
        const int p00 = 2 * pm, p10 = 64 + 2 * pm;
        const float v = fmaxf(fmaxf(buf[p00 * 49 + j], buf[(p00 + 1) * 49 + j]),
                              fmaxf(buf[p10 * 49 + j], buf[(p10 + 1) * 49 + j]));
        const int m = hp * 32 + pm;
        if (j < 8) phiP[((size_t)b * MM + m) * 8 + j] = f2bf(v);
        else       gP[((size_t)b * 32 + (j - 8)) * MM + m] = f2bf(v);
    }
}

// ---------------------------------------------------------------------------
// attn_mfma v4: PV via 16x16x32 (full-rate, K=32) + MFMA epilogue.
//  - phi is staged SLOT-PERMUTED: key q*8+r -> slot q*4+r, key q*8+4+r ->
//    slot 16+q*4+r (within each 32-key group). The two x16 score MFMAs per
//    group then give lane (c15,quad) exactly keys quad*8+0..7 = the x32 PV
//    A-frag layout; packed with the same 4 v_perms as before.
//  - g B-frags become one ds_read_b128 per 32 keys (was 2x b64 per 16).
//  - epilogue: out[o][q] = x + sg*Wa[o][:32].obar[q][:32] as 4 x32 MFMAs per
//    wave; Wa held as a per-lane bf16 A-frag in registers (wa_s LDS dropped),
//    obar stored as bf16 rows [64][40] in LDS (rounding adds ~2e-3 abs err,
//    negligible vs the existing 0.031 from bf16 P/theta/phi/g).
// Grid (64,16), block 256. LDS 21 KB (was 29.2 KB).
// ---------------------------------------------------------------------------
__global__ __launch_bounds__(256) void attn_mfma(
    const unsigned short* __restrict__ thT,   // [B][N][8]
    const unsigned short* __restrict__ phiP,  // [B][M][8]
    const unsigned short* __restrict__ gP,    // [B][32][M]
    const float* __restrict__ x,
    const float* __restrict__ Wa,             // [64][32]
    const float* __restrict__ sigma,
    float* __restrict__ out)
{
    constexpr int GP = 264;   // g_s pitch (bf16): 528 B = 33x16 -> aligned rows
    constexpr int OBP = 40;   // obb pitch (bf16): 80 B = 5x16 -> aligned rows

    __shared__ __align__(16) union {
        struct {
            unsigned short phi[256 * 8 + 16];  // pad: slot-255 quad2/3 overread
            unsigned short g[32 * GP];
        } m;                                    // 21.0 KB
        unsigned short obb[64 * OBP];           // 5.1 KB (epilogue)
    } sh;

    const int tid  = threadIdx.x;
    const int lane = tid & 63;
    const int wv   = tid >> 6;
    const int c15  = lane & 15;     // score D col = query; PV D col = gi
    const int quad = lane >> 4;
    const int b    = blockIdx.y;
    const int n0   = blockIdx.x * 64;

    // Wa A-frag in registers: A[m=c15 -> o=wv*16+c15][k=quad*8+j -> gi]
    union { unsigned short s[8]; s8b v; } wfrag;
    {
        const float* wr = Wa + (wv * 16 + c15) * 32 + quad * 8;
        const float4 w0 = *(const float4*)wr;
        const float4 w1 = *(const float4*)(wr + 4);
        wfrag.s[0] = f2bf(w0.x); wfrag.s[1] = f2bf(w0.y);
        wfrag.s[2] = f2bf(w0.z); wfrag.s[3] = f2bf(w0.w);
        wfrag.s[4] = f2bf(w1.x); wfrag.s[5] = f2bf(w1.y);
        wfrag.s[6] = f2bf(w1.z); wfrag.s[7] = f2bf(w1.w);
    }

    // theta B-frag (const): B[k=quad*4+j][n=q]; real only for quads 0,1 (k<8)
    s4b zero4 = {0, 0, 0, 0};
    s4b bth = zero4;
    if (quad < 2) {
        union { uint2 u; s4b s; } t;
        t.u = *(const uint2*)&thT[((size_t)b * NN + n0 + wv * 16 + c15) * 8 + quad * 4];
        bth = t.s;
    }

    float4v acc0 = {0.f, 0.f, 0.f, 0.f};
    float4v acc1 = {0.f, 0.f, 0.f, 0.f};
    float zacc = 0.f;

    for (int ch = 0; ch < 4; ++ch) {
        __syncthreads();
        // stage phi slot-permuted (+ zero the pad). key k = tid within chunk:
        // r=k&7, q3=(k>>3)&3 -> slot = (k&~31) | ((r>>2)<<4) | (q3<<2) | (r&3)
        {
            const int r  = tid & 7;
            const int q3 = (tid >> 3) & 3;
            const int slot = (tid & ~31) | ((r >> 2) << 4) | (q3 << 2) | (r & 3);
            *(uint4*)&sh.m.phi[slot * 8] =
                *(const uint4*)&phiP[((size_t)b * MM + ch * 256 + tid) * 8];
            if (tid < 2) {
                uint4 z4; z4.x = z4.y = z4.z = z4.w = 0u;
                *(uint4*)&sh.m.phi[256 * 8 + tid * 8] = z4;
            }
        }
        // stage g: 32 rows x 256 bf16 = 1024 uint4 (rows 16B-aligned), linear
#pragma unroll
        for (int it = 0; it < 4; ++it) {
            const int idx = tid + 256 * it;
            const int row = idx >> 5, c32 = idx & 31;
            *(uint4*)&sh.m.g[row * GP + c32 * 8] =
                *(const uint4*)&gP[((size_t)b * 32 + row) * MM + ch * 256 + c32 * 8];
        }
        __syncthreads();

        const unsigned short* pA  = &sh.m.phi[c15 * 8 + quad * 4];
        const unsigned short* pg0 = &sh.m.g[c15 * GP + quad * 8];
        const unsigned short* pg1 = pg0 + 16 * GP;

#pragma unroll
        for (int g32 = 0; g32 < 8; ++g32) {
            // score A-frags: slots kb+c15 (keys quad*8+0..3) and kb+16+c15
            // (keys quad*8+4..7); quads 2,3 read neighbor rows (finite) x B=0
            union { uint2 u; s4b s; } apA, apB;
            apA.u = *(const uint2*)&pA[g32 * 256];
            apB.u = *(const uint2*)&pA[g32 * 256 + 128];

            float4v cz = {0.f, 0.f, 0.f, 0.f};
            float4v scA = mfma16(apA.s, bth, cz);   // D[key=quad*8+r][q=c15]
            float4v scB = mfma16(apB.s, bth, cz);   // D[key=quad*8+4+r][q=c15]

            // exp2 + Z + pack P (truncating bf16) -> x32 PV A-frag in-register
            union { float f; unsigned u; } a0, a1, a2, a3, b0, b1, b2, b3;
            a0.f = __builtin_amdgcn_exp2f(scA[0]);
            a1.f = __builtin_amdgcn_exp2f(scA[1]);
            a2.f = __builtin_amdgcn_exp2f(scA[2]);
            a3.f = __builtin_amdgcn_exp2f(scA[3]);
            b0.f = __builtin_amdgcn_exp2f(scB[0]);
            b1.f = __builtin_amdgcn_exp2f(scB[1]);
            b2.f = __builtin_amdgcn_exp2f(scB[2]);
            b3.f = __builtin_amdgcn_exp2f(scB[3]);
            zacc += ((a0.f + a1.f) + (a2.f + a3.f)) +
                    ((b0.f + b1.f) + (b2.f + b3.f));
            union { uint4 u; s8b s; } pa;
            pa.u.x = __builtin_amdgcn_perm(a1.u, a0.u, 0x07060302u);
            pa.u.y = __builtin_amdgcn_perm(a3.u, a2.u, 0x07060302u);
            pa.u.z = __builtin_amdgcn_perm(b1.u, b0.u, 0x07060302u);
            pa.u.w = __builtin_amdgcn_perm(b3.u, b2.u, 0x07060302u);

            // g B-frags: B[k=quad*8+j][n=gi=c15] = g[gi][kb+quad*8+j]
            union { uint4 u; s8b s; } bg0, bg1;
            bg0.u = *(const uint4*)&pg0[g32 * 32];
            bg1.u = *(const uint4*)&pg1[g32 * 32];

            acc0 = mfma32(pa.s, bg0.s, acc0);   // D[q=quad*4+r][gi=c15]
            acc1 = mfma32(pa.s, bg1.s, acc1);   // gi = c15+16
        }
    }

    // full Z per query at every lane (q = c15)
    float z = zacc;
    z += __shfl_xor(z, 16, 64);
    z += __shfl_xor(z, 32, 64);
    const float rzq = __builtin_amdgcn_rcpf(z);

    __syncthreads();   // main-loop LDS reads done before obb overwrites

    // obar -> bf16 LDS rows [q][gi], pitch 40 (80 B, 16B-aligned)
#pragma unroll
    for (int r = 0; r < 4; ++r) {
        const float rz = __shfl(rzq, quad * 4 + r, 64);  // Z of query quad*4+r
        const int ql = wv * 16 + quad * 4 + r;
        sh.obb[ql * OBP + c15]      = f2bf(acc0[r] * rz);
        sh.obb[ql * OBP + 16 + c15] = f2bf(acc1[r] * rz);
    }
    __syncthreads();

    // epilogue: out[o][q] = x + sigma * Wa[o][:32] . obar[q][:32]
    // one x32 MFMA per 16-query tile: A = wfrag, B[k=gi=quad*8+j][n=q=c15]
    const float sg = sigma[0];
#pragma unroll
    for (int t = 0; t < 4; ++t) {
        union { uint4 u; s8b s; } bo;
        bo.u = *(const uint4*)&sh.obb[(t * 16 + c15) * OBP + quad * 8];
        float4v cz = {0.f, 0.f, 0.f, 0.f};
        float4v oc = mfma32(wfrag.v, bo.s, cz);   // D[o=wv*16+quad*4+r][q=c15]
#pragma unroll
        for (int r = 0; r < 4; ++r) {
            const size_t oi = ((size_t)b * CC + wv * 16 + quad * 4 + r) * NN
                              + n0 + t * 16 + c15;
            out[oi] = x[oi] + sg * oc[r];
        }
    }
}

extern "C" void kernel_launch(void* const* d_in, const int* in_sizes, int n_in,
                              void* d_out, int out_size, void* d_ws, size_t ws_size,
                              hipStream_t stream) {
    const float* x      = (const float*)d_in[0];
    const float* W_th   = (const float*)d_in[1];
    const float* W_ph   = (const float*)d_in[2];
    const float* W_g    = (const float*)d_in[3];
    const float* W_attn = (const float*)d_in[4];
    const float* sigma  = (const float*)d_in[5];
    float* out = (float*)d_out;

    const int B = 16;
    unsigned short* thT  = (unsigned short*)d_ws;              // B*N*8
    unsigned short* phiP = thT + (size_t)B * NN * 8;           // B*M*8
    unsigned short* gP   = phiP + (size_t)B * MM * 8;          // B*32*M

    prep_kernel<<<dim3(32, 16), 256, 0, stream>>>(x, W_th, W_ph, W_g,
                                                  thT, phiP, gP);
    attn_mfma<<<dim3(64, 16), 256, 0, stream>>>(thT, phiP, gP, x,
                                                W_attn, sigma, out);
}